// Round 6
// baseline (198.448 us; speedup 1.0000x reference)
//
#include <hip/hip_runtime.h>
#include <stdint.h>

// Problem constants (fixed by the reference)
#define B_IMG        64
#define M_GT         100
#define N_PROP       4000
#define K_TOT        4100          // N + M (proposal_append_gt)
#define NUM_CLASSES_ 80
#define BATCH_PER    512
#define NUM_FG_TGT   128
#define OUT_STRIDE   (B_IMG * BATCH_PER)   // 32768 elements per output tensor

#define NT           512                   // threads per block (fused kernel)
#define PPB          8                     // producer blocks per image
#define SLICE        513                   // ceil(4100/8)
#define HALF_CAP     1024                  // candidate capacity per group (fg | bg)

// ws layout: [ghist: B*2*256 u32 = 128 KiB][pad to 132096: ctr B u32][keys B*K u64]
#define HIST_WORDS   (B_IMG * 2 * 256)
#define CTR_OFF_W    HIST_WORDS                      // word offset of ctr
#define ZERO_BYTES   (HIST_WORDS * 4 + 1024)         // 132096, 8-aligned
#define NTF          1024                  // threads per block (fallback kernel)

// Key packing (uint64 compare gives exact (fg, pri, idx) descending order;
// midx rides in the low bits — idx is unique so it never affects ordering):
//   bit 50      : fg flag
//   bits 49..20 : float bits of priority (pri in [0,1) => bits < 2^30;
//                 positive-float bits are order-isomorphic to values)
//   bits 19..7  : element index (0..4099 < 8192)  — reproduces the reversed-
//                 stable-argsort tiebreak (higher idx first on equal pri)
//   bits  6..0  : matched gt index (0..99 < 128)

// IoU with contraction disabled so float32 results match the numpy reference
// bit-for-bit (an FMA-induced 1-ulp drift at the 0.5 threshold would flip
// fg/bg and scramble integer outputs).
__device__ __forceinline__ float iou_fn(float ax1, float ay1, float ax2, float ay2,
                                        float area_a,
                                        float bx1, float by1, float bx2, float by2,
                                        float area_b) {
#pragma clang fp contract(off)
    float ltx = fmaxf(ax1, bx1), lty = fmaxf(ay1, by1);
    float rbx = fminf(ax2, bx2), rby = fminf(ay2, by2);
    float wx = fmaxf(rbx - ltx, 0.0f);
    float wy = fmaxf(rby - lty, 0.0f);
    float inter = wx * wy;
    float uni = area_a + area_b - inter;
    return inter > 0.0f ? inter / uni : 0.0f;
}

// ---------------------------------------------------------------------------
// Fused chip-wide kernel. Grid = B_IMG*PPB = 512 blocks x 512 threads.
// Block blk: image b = blk>>3, slice p = blk&7.
//   Phase A (all blocks): IoU argmax + key build for its slice -> ws keys;
//                         local LDS histogram -> merged to ws ghist.
//   Handoff: __syncthreads + __threadfence + release-add on ctr[b] (R5-proven);
//            owner (p==0) relaxed-spins, then one block-wide acquire fence.
//   Phase B (64 owners): suffix-scan ghist, threshold, compact from global
//                        keys, O(k^2)-broadcast rank, emit.
// Deadlock-free: 512 thr (8 waves) + ~31 KiB LDS + VGPR<=64 => >=4 blocks/CU
// capacity = 1024 >= 512 grid: all blocks co-resident, no ordering assumed.
// ---------------------------------------------------------------------------
__global__ __launch_bounds__(NT, 8) void fused_kernel(
        const float* __restrict__ gt_boxes,    // [B, M, 4]
        const float* __restrict__ prop_boxes,  // [B, N, 4]
        const int*   __restrict__ gt_classes,  // [B, M]
        const float* __restrict__ rand_pri,    // [B, K]
        uint32_t*    __restrict__ ghist,       // [B][2][256] in ws (zeroed)
        uint32_t*    __restrict__ ctr,         // [B] arrival counters (zeroed)
        uint64_t*    __restrict__ keys,        // [B, K] in ws
        float*       __restrict__ out)         // 5 x [B, 512] flat
{
    __shared__ uint64_t s_cand[2 * HALF_CAP];  // 16 KB: fg half | bg half
    __shared__ float    s_out[5][BATCH_PER];   // 10 KB staging
    __shared__ int      s_hist[2][256];        // 2 KB
    __shared__ float    s_gtb[M_GT * 4];
    __shared__ float    s_gta[M_GT];
    __shared__ int      s_gtc[M_GT];
    __shared__ int      s_T[2], s_needed[2], s_cnt[2];

    const int blk = blockIdx.x;
    const int b   = blk >> 3;
    const int p   = blk & 7;
    const int tid = threadIdx.x;

    // ---- stage gt data for image b; zero local histogram ----
    for (int i = tid; i < 512; i += NT) s_hist[i >> 8][i & 255] = 0;
    for (int i = tid; i < M_GT * 4; i += NT)
        s_gtb[i] = gt_boxes[(size_t)b * M_GT * 4 + i];
    for (int i = tid; i < M_GT; i += NT)
        s_gtc[i] = gt_classes[(size_t)b * M_GT + i];
    __syncthreads();
    for (int m = tid; m < M_GT; m += NT) {
#pragma clang fp contract(off)
        s_gta[m] = (s_gtb[m * 4 + 2] - s_gtb[m * 4 + 0]) *
                   (s_gtb[m * 4 + 3] - s_gtb[m * 4 + 1]);
    }
    __syncthreads();

    // ---- phase A: IoU argmax + key build for slice p ----
    const int kend = min((p + 1) * SLICE, K_TOT);
    for (int k = p * SLICE + tid; k < kend; k += NT) {
        float bx1, by1, bx2, by2;
        if (k < N_PROP) {
            const float4 bp = *(const float4*)(prop_boxes + ((size_t)b * N_PROP + k) * 4);
            bx1 = bp.x; by1 = bp.y; bx2 = bp.z; by2 = bp.w;
        } else {
            const float* bp = s_gtb + (k - N_PROP) * 4;
            bx1 = bp[0]; by1 = bp[1]; bx2 = bp[2]; by2 = bp[3];
        }
        float area_b;
        {
#pragma clang fp contract(off)
            area_b = (bx2 - bx1) * (by2 - by1);
        }
        float best = -1.0f; int bidx = 0;
        for (int m = 0; m < M_GT; ++m) {
            float iv = iou_fn(s_gtb[m*4+0], s_gtb[m*4+1], s_gtb[m*4+2], s_gtb[m*4+3],
                              s_gta[m], bx1, by1, bx2, by2, area_b);
            if (iv > best) { best = iv; bidx = m; }  // strict > => first-occurrence argmax
        }
        const bool fg = best >= 0.5f;
        const float pri = rand_pri[(size_t)b * K_TOT + k];
        const uint32_t pb = __float_as_uint(pri);
        keys[(size_t)b * K_TOT + k] =
              (fg ? (1ull << 50) : 0ull)
            | ((uint64_t)pb << 20)
            | ((uint64_t)k  << 7)
            | (uint64_t)bidx;
        int bucket = min(255, (int)(pri * 256.0f));   // monotone in pri
        atomicAdd(&s_hist[fg ? 0 : 1][bucket], 1);
    }
    __syncthreads();

    // merge local histogram into the per-image global histogram
    for (int i = tid; i < 512; i += NT) {
        int v = s_hist[i >> 8][i & 255];
        if (v) atomicAdd(&ghist[(size_t)b * 512 + i], (uint32_t)v);
    }
    __syncthreads();
    __threadfence();                            // drain key/hist stores device-wide
    if (tid == 0)
        __hip_atomic_fetch_add(&ctr[b], 1u, __ATOMIC_RELEASE, __HIP_MEMORY_SCOPE_AGENT);
    if (p != 0) return;                         // producers done

    // ---- owner: relaxed spin for all 8 producers, then one acquire fence ----
    if (tid == 0) {
        while (__hip_atomic_load(&ctr[b], __ATOMIC_RELAXED, __HIP_MEMORY_SCOPE_AGENT) < (uint32_t)PPB)
            __builtin_amdgcn_s_sleep(2);
    }
    __syncthreads();
    __builtin_amdgcn_fence(__ATOMIC_ACQUIRE, "agent");   // per-thread, once

    // ---- phase B: load merged histogram, suffix-scan, threshold ----
    for (int i = tid; i < 512; i += NT)
        s_hist[i >> 8][i & 255] = (int)ghist[(size_t)b * 512 + i];
    if (tid < 2) s_cnt[tid] = 0;
    __syncthreads();

    for (int d = 1; d < 256; d <<= 1) {         // Hillis-Steele suffix scan
        int v = 0, g = tid >> 8, t = tid & 255;
        bool act = (t + d < 256);               // NT=512 covers both histograms
        if (act) v = s_hist[g][t + d];
        __syncthreads();
        if (act) s_hist[g][t] += v;
        __syncthreads();
    }

    if (tid == 0) {
        int fg_total = s_hist[0][0];
        int bg_total = s_hist[1][0];
        int nfg = min(NUM_FG_TGT, fg_total);
        int nbg = min(BATCH_PER - nfg, bg_total);
        s_needed[0] = nfg; s_needed[1] = nbg;
    }
    __syncthreads();

    // bucket threshold: max t with S[t] >= need (unique crossing; S non-increasing)
    {
        int g = tid >> 8, t = tid & 255;
        int need = s_needed[g];
        int St  = s_hist[g][t];
        int St1 = (t == 255) ? -1 : s_hist[g][t + 1];
        if (St >= need && St1 < need) s_T[g] = t;
    }
    if (tid < BATCH_PER) {                      // prefill invalid pattern
        s_out[0][tid] = 0.0f; s_out[1][tid] = -1.0f;
        s_out[2][tid] = -1.0f; s_out[3][tid] = -1.0f;
    }
    __syncthreads();

    const int nfg = s_needed[0], nbg = s_needed[1];
    if (tid < BATCH_PER)
        s_out[4][tid] = (tid < nfg + nbg) ? 1.0f : 0.0f;

    // compaction from global keys into disjoint halves
    for (int k = tid; k < K_TOT; k += NT) {
        uint64_t key = keys[(size_t)b * K_TOT + k];
        int g = ((key >> 50) & 1ull) ? 0 : 1;
        uint32_t pbits = (uint32_t)((key >> 20) & 0x3FFFFFFFull);
        int bucket = min(255, (int)(__uint_as_float(pbits) * 256.0f));
        if (bucket >= s_T[g]) {
            int pos = atomicAdd(&s_cnt[g], 1);
            if (pos < HALF_CAP) s_cand[g * HALF_CAP + pos] = key;
        }
    }
    __syncthreads();

    // rank within each half (keys unique -> each slot written exactly once,
    // independent of atomic ordering) and emit
    const int fgc = min(s_cnt[0], HALF_CAP);
    const int bgc = min(s_cnt[1], HALF_CAP);
    for (int c = tid; c < fgc + bgc; c += NT) {
        const bool isfg = (c < fgc);
        const int  base = isfg ? 0 : HALF_CAP;
        const int  cnt  = isfg ? fgc : bgc;
        const int  ci   = isfg ? c : (c - fgc);
        const uint64_t kc = s_cand[base + ci];
        int r = 0;
        for (int j = 0; j < cnt; ++j)           // broadcast LDS reads
            r += (s_cand[base + j] > kc) ? 1 : 0;
        int slot = -1;
        if (isfg) { if (r < nfg) slot = r; }
        else      { if (r < nbg) slot = nfg + r; }
        if (slot >= 0) {
            int idx = (int)((kc >> 7) & 0x1FFFull);
            int mi  = (int)(kc & 0x7Full);
            float bx1, by1, bx2, by2;
            if (idx < N_PROP) {
                const float4 bp = *(const float4*)(prop_boxes + ((size_t)b * N_PROP + idx) * 4);
                bx1 = bp.x; by1 = bp.y; bx2 = bp.z; by2 = bp.w;
            } else {
                const float* bp = s_gtb + (idx - N_PROP) * 4;
                bx1 = bp[0]; by1 = bp[1]; bx2 = bp[2]; by2 = bp[3];
            }
            float area_b;
            {
#pragma clang fp contract(off)
                area_b = (bx2 - bx1) * (by2 - by1);
            }
            // bit-exact matched_vals[idx]: same fp ops on same inputs as phase A
            float iou = iou_fn(s_gtb[mi*4+0], s_gtb[mi*4+1], s_gtb[mi*4+2], s_gtb[mi*4+3],
                               s_gta[mi], bx1, by1, bx2, by2, area_b);
            s_out[0][slot] = iou;
            s_out[1][slot] = (float)idx;
            s_out[2][slot] = (float)(isfg ? s_gtc[mi] : NUM_CLASSES_);
            s_out[3][slot] = (float)mi;
        }
    }
    __syncthreads();

    // coalesced write-out
    for (int i = tid; i < 5 * BATCH_PER; i += NT) {
        int o = i / BATCH_PER, q = i % BATCH_PER;
        out[(size_t)o * OUT_STRIDE + (size_t)b * BATCH_PER + q] = s_out[o][q];
    }
}

// ---------------------------------------------------------------------------
// Fallback: R4's proven single kernel (one block per image, zero workspace).
// Used only if ws_size is too small.
// ---------------------------------------------------------------------------
__global__ __launch_bounds__(NTF) void roiheads_fallback(
        const float* __restrict__ gt_boxes,
        const float* __restrict__ prop_boxes,
        const int*   __restrict__ gt_classes,
        const float* __restrict__ rand_pri,
        float*       __restrict__ out)
{
    __shared__ uint64_t s_keys[K_TOT];
    __shared__ uint64_t s_cand[2 * HALF_CAP];
    __shared__ int      s_hist[2][256];
    __shared__ float    s_gtb[M_GT * 4];
    __shared__ float    s_gta[M_GT];
    __shared__ int      s_gtc[M_GT];
    __shared__ float    s_out[5][BATCH_PER];
    __shared__ int      s_T[2], s_needed[2], s_cnt[2];

    const int b   = blockIdx.x;
    const int tid = threadIdx.x;

    for (int i = tid; i < 512; i += NTF) s_hist[i >> 8][i & 255] = 0;
    if (tid < 2) s_cnt[tid] = 0;
    for (int i = tid; i < M_GT * 4; i += NTF)
        s_gtb[i] = gt_boxes[(size_t)b * M_GT * 4 + i];
    for (int i = tid; i < M_GT; i += NTF)
        s_gtc[i] = gt_classes[(size_t)b * M_GT + i];
    __syncthreads();
    for (int m = tid; m < M_GT; m += NTF) {
#pragma clang fp contract(off)
        s_gta[m] = (s_gtb[m * 4 + 2] - s_gtb[m * 4 + 0]) *
                   (s_gtb[m * 4 + 3] - s_gtb[m * 4 + 1]);
    }
    __syncthreads();

    for (int k = tid; k < K_TOT; k += NTF) {
        float bx1, by1, bx2, by2;
        if (k < N_PROP) {
            const float4 bp = *(const float4*)(prop_boxes + ((size_t)b * N_PROP + k) * 4);
            bx1 = bp.x; by1 = bp.y; bx2 = bp.z; by2 = bp.w;
        } else {
            const float* bp = s_gtb + (k - N_PROP) * 4;
            bx1 = bp[0]; by1 = bp[1]; bx2 = bp[2]; by2 = bp[3];
        }
        float area_b;
        {
#pragma clang fp contract(off)
            area_b = (bx2 - bx1) * (by2 - by1);
        }
        float best = -1.0f; int bidx = 0;
        for (int m = 0; m < M_GT; ++m) {
            float iv = iou_fn(s_gtb[m*4+0], s_gtb[m*4+1], s_gtb[m*4+2], s_gtb[m*4+3],
                              s_gta[m], bx1, by1, bx2, by2, area_b);
            if (iv > best) { best = iv; bidx = m; }
        }
        const bool fg = best >= 0.5f;
        const float pri = rand_pri[(size_t)b * K_TOT + k];
        const uint32_t pb = __float_as_uint(pri);
        s_keys[k] = (fg ? (1ull << 50) : 0ull)
                  | ((uint64_t)pb << 20)
                  | ((uint64_t)k  << 7)
                  | (uint64_t)bidx;
        int bucket = min(255, (int)(pri * 256.0f));
        atomicAdd(&s_hist[fg ? 0 : 1][bucket], 1);
    }
    __syncthreads();

    for (int d = 1; d < 256; d <<= 1) {
        int v = 0, g = tid >> 8, t = tid & 255;
        bool act = (tid < 512) && (t + d < 256);
        if (act) v = s_hist[g][t + d];
        __syncthreads();
        if (act) s_hist[g][t] += v;
        __syncthreads();
    }

    if (tid == 0) {
        int fg_total = s_hist[0][0];
        int bg_total = s_hist[1][0];
        int nfg = min(NUM_FG_TGT, fg_total);
        int nbg = min(BATCH_PER - nfg, bg_total);
        s_needed[0] = nfg; s_needed[1] = nbg;
    }
    __syncthreads();

    if (tid < 512) {
        int g = tid >> 8, t = tid & 255;
        int need = s_needed[g];
        int St  = s_hist[g][t];
        int St1 = (t == 255) ? -1 : s_hist[g][t + 1];
        if (St >= need && St1 < need) s_T[g] = t;
    }
    if (tid < BATCH_PER) {
        s_out[0][tid] = 0.0f; s_out[1][tid] = -1.0f;
        s_out[2][tid] = -1.0f; s_out[3][tid] = -1.0f;
    }
    __syncthreads();

    const int nfg = s_needed[0], nbg = s_needed[1];
    if (tid < BATCH_PER)
        s_out[4][tid] = (tid < nfg + nbg) ? 1.0f : 0.0f;

    for (int k = tid; k < K_TOT; k += NTF) {
        uint64_t key = s_keys[k];
        int g = ((key >> 50) & 1ull) ? 0 : 1;
        uint32_t pbits = (uint32_t)((key >> 20) & 0x3FFFFFFFull);
        int bucket = min(255, (int)(__uint_as_float(pbits) * 256.0f));
        if (bucket >= s_T[g]) {
            int pos = atomicAdd(&s_cnt[g], 1);
            if (pos < HALF_CAP) s_cand[g * HALF_CAP + pos] = key;
        }
    }
    __syncthreads();

    const int fgc = min(s_cnt[0], HALF_CAP);
    const int bgc = min(s_cnt[1], HALF_CAP);
    for (int c = tid; c < fgc + bgc; c += NTF) {
        const bool isfg = (c < fgc);
        const int  base = isfg ? 0 : HALF_CAP;
        const int  cnt  = isfg ? fgc : bgc;
        const int  ci   = isfg ? c : (c - fgc);
        const uint64_t kc = s_cand[base + ci];
        int r = 0;
        for (int j = 0; j < cnt; ++j)
            r += (s_cand[base + j] > kc) ? 1 : 0;
        int slot = -1;
        if (isfg) { if (r < nfg) slot = r; }
        else      { if (r < nbg) slot = nfg + r; }
        if (slot >= 0) {
            int idx = (int)((kc >> 7) & 0x1FFFull);
            int mi  = (int)(kc & 0x7Full);
            float bx1, by1, bx2, by2;
            if (idx < N_PROP) {
                const float4 bp = *(const float4*)(prop_boxes + ((size_t)b * N_PROP + idx) * 4);
                bx1 = bp.x; by1 = bp.y; bx2 = bp.z; by2 = bp.w;
            } else {
                const float* bp = s_gtb + (idx - N_PROP) * 4;
                bx1 = bp[0]; by1 = bp[1]; bx2 = bp[2]; by2 = bp[3];
            }
            float area_b;
            {
#pragma clang fp contract(off)
                area_b = (bx2 - bx1) * (by2 - by1);
            }
            float iou = iou_fn(s_gtb[mi*4+0], s_gtb[mi*4+1], s_gtb[mi*4+2], s_gtb[mi*4+3],
                               s_gta[mi], bx1, by1, bx2, by2, area_b);
            s_out[0][slot] = iou;
            s_out[1][slot] = (float)idx;
            s_out[2][slot] = (float)(isfg ? s_gtc[mi] : NUM_CLASSES_);
            s_out[3][slot] = (float)mi;
        }
    }
    __syncthreads();

    for (int i = tid; i < 5 * BATCH_PER; i += NTF) {
        int o = i / BATCH_PER, q = i % BATCH_PER;
        out[(size_t)o * OUT_STRIDE + (size_t)b * BATCH_PER + q] = s_out[o][q];
    }
}

extern "C" void kernel_launch(void* const* d_in, const int* in_sizes, int n_in,
                              void* d_out, int out_size, void* d_ws, size_t ws_size,
                              hipStream_t stream) {
    const float* gt_boxes   = (const float*)d_in[0];  // [64,100,4]
    const float* prop_boxes = (const float*)d_in[1];  // [64,4000,4]
    const int*   gt_classes = (const int*)  d_in[2];  // [64,100]
    const float* rand_pri   = (const float*)d_in[3];  // [64,4100]
    float* out = (float*)d_out;                       // 5 x [64,512] float32, concat

    const size_t need_ws = ZERO_BYTES + (size_t)B_IMG * K_TOT * sizeof(uint64_t);
    if (d_ws != nullptr && ws_size >= need_ws) {
        uint32_t* ghist = (uint32_t*)d_ws;
        uint32_t* ctr   = (uint32_t*)d_ws + CTR_OFF_W;
        uint64_t* keys  = (uint64_t*)((char*)d_ws + ZERO_BYTES);
        // zero histograms + arrival counters (captured into graph, stream-ordered)
        hipMemsetAsync(d_ws, 0, ZERO_BYTES, stream);
        fused_kernel<<<B_IMG * PPB, NT, 0, stream>>>(gt_boxes, prop_boxes,
                                                     gt_classes, rand_pri,
                                                     ghist, ctr, keys, out);
    } else {
        roiheads_fallback<<<B_IMG, NTF, 0, stream>>>(gt_boxes, prop_boxes,
                                                     gt_classes, rand_pri, out);
    }
}

// Round 7
// 189.480 us; speedup vs baseline: 1.0473x; 1.0473x over previous
//
#include <hip/hip_runtime.h>
#include <stdint.h>

// Problem constants (fixed by the reference)
#define B_IMG        64
#define M_GT         100
#define N_PROP       4000
#define K_TOT        4100          // N + M (proposal_append_gt)
#define NUM_CLASSES_ 80
#define BATCH_PER    512
#define NUM_FG_TGT   128
#define OUT_STRIDE   (B_IMG * BATCH_PER)   // 32768 elements per output tensor

#define NTH          1024                  // threads per block
#define HALF_CAP     1024                  // candidate capacity per group (fg | bg)
#define QPI          4                     // producer blocks (quarters) per image
#define QLEN         1025                  // K_TOT / QPI
#define CTR_BYTES    1024                  // arrival-counter region at front of ws

// Key packing (uint64 compare gives exact (fg, pri, idx) descending order;
// midx rides in the low bits — idx is unique so it never affects ordering):
//   bit 50      : fg flag
//   bits 49..20 : float bits of priority (pri in [0,1) => bits < 2^30;
//                 positive-float bits are order-isomorphic to values)
//   bits 19..7  : element index (0..4099 < 8192)  — reproduces the reversed-
//                 stable-argsort tiebreak (higher idx first on equal pri)
//   bits  6..0  : matched gt index (0..99 < 128)

// IoU with contraction disabled so float32 results match the numpy reference
// bit-for-bit. area_a is computed in-register from the float4 with the exact
// same expression previously used for the precomputed area array — same bits.
__device__ __forceinline__ float iou_g(float4 g,
                                       float bx1, float by1, float bx2, float by2,
                                       float area_b) {
#pragma clang fp contract(off)
    float area_a = (g.z - g.x) * (g.w - g.y);
    float ltx = fmaxf(g.x, bx1), lty = fmaxf(g.y, by1);
    float rbx = fminf(g.z, bx2), rby = fminf(g.w, by2);
    float wx = fmaxf(rbx - ltx, 0.0f);
    float wy = fmaxf(rby - lty, 0.0f);
    float inter = wx * wy;
    float uni = area_a + area_b - inter;
    return inter > 0.0f ? inter / uni : 0.0f;
}

// ---------------------------------------------------------------------------
// Fused chip-wide kernel (R5 skeleton + ILP'd inner loop).
// Grid = B_IMG*QPI = 256 blocks x 1024 threads. Block blk: b = blk>>2, q = blk&3.
//   Phase A (all blocks): IoU argmax (4x-unrolled, float4 LDS reads) + key
//                         build for its quarter -> ws keys.
//   Handoff: __syncthreads + __threadfence + release-add on ctr[b];
//            owner (q==0) relaxed-spins, then one block-wide acquire fence.
//   Phase B (64 owners): stage keys to LDS + histogram, suffix-scan,
//                        threshold, compact, O(k^2)-broadcast rank, emit.
// Deadlock-free: __launch_bounds__(1024,6) => VGPR<=~85 => >=24 waves/CU =>
// >=1 block/CU; LDS ~63KB => 2 blocks/CU; grid 256 <= 256 CUs co-resident.
// ---------------------------------------------------------------------------
__global__ __launch_bounds__(NTH, 6) void fused_kernel(
        const float* __restrict__ gt_boxes,    // [B, M, 4]
        const float* __restrict__ prop_boxes,  // [B, N, 4]
        const int*   __restrict__ gt_classes,  // [B, M]
        const float* __restrict__ rand_pri,    // [B, K]
        uint64_t*    __restrict__ keys,        // [B, K] in ws (after ctr region)
        uint32_t*    __restrict__ ctr,         // [B] arrival counters (zeroed)
        float*       __restrict__ out)         // 5 x [B, 512] flat
{
    __shared__ uint64_t s_keys[K_TOT];         // 32.8 KB (owner phase B)
    __shared__ uint64_t s_cand[2 * HALF_CAP];  // 16 KB: fg half | bg half
    __shared__ int      s_hist[2][256];        // 2 KB
    __shared__ float4   s_gtb4[M_GT];          // 1.6 KB gt boxes as float4
    __shared__ int      s_gtc[M_GT];
    __shared__ float    s_out[5][BATCH_PER];   // 10 KB staging
    __shared__ int      s_T[2], s_needed[2], s_cnt[2];

    const int blk = blockIdx.x;
    const int b   = blk >> 2;
    const int q   = blk & 3;
    const int tid = threadIdx.x;

    // ---- stage gt data for image b ----
    for (int i = tid; i < M_GT; i += NTH)
        s_gtb4[i] = ((const float4*)gt_boxes)[(size_t)b * M_GT + i];
    for (int i = tid; i < M_GT; i += NTH)
        s_gtc[i] = gt_classes[(size_t)b * M_GT + i];
    __syncthreads();

    // ---- phase A: IoU argmax + key build for quarter q (4x unrolled) ----
    for (int t = tid; t < QLEN; t += NTH) {
        const int k = q * QLEN + t;            // 4*1025 == 4100: always < K_TOT
        float bx1, by1, bx2, by2;
        if (k < N_PROP) {
            const float4 bp = *(const float4*)(prop_boxes + ((size_t)b * N_PROP + k) * 4);
            bx1 = bp.x; by1 = bp.y; bx2 = bp.z; by2 = bp.w;
        } else {
            const float4 bp = s_gtb4[k - N_PROP];
            bx1 = bp.x; by1 = bp.y; bx2 = bp.z; by2 = bp.w;
        }
        float area_b;
        {
#pragma clang fp contract(off)
            area_b = (bx2 - bx1) * (by2 - by1);
        }
        float best = -1.0f; int bidx = 0;
        // 4x unroll: 4 independent IoU chains per iteration; the comparison
        // tree preserves first-occurrence argmax exactly (a later index wins
        // only on strict >, and every b-side index exceeds every a-side one).
        for (int m = 0; m < M_GT; m += 4) {
            float4 g0 = s_gtb4[m + 0];
            float4 g1 = s_gtb4[m + 1];
            float4 g2 = s_gtb4[m + 2];
            float4 g3 = s_gtb4[m + 3];
            float q0 = iou_g(g0, bx1, by1, bx2, by2, area_b);
            float q1 = iou_g(g1, bx1, by1, bx2, by2, area_b);
            float q2 = iou_g(g2, bx1, by1, bx2, by2, area_b);
            float q3 = iou_g(g3, bx1, by1, bx2, by2, area_b);
            float qa; int ia;
            if (q1 > q0) { qa = q1; ia = m + 1; } else { qa = q0; ia = m; }
            float qb; int ib;
            if (q3 > q2) { qb = q3; ib = m + 3; } else { qb = q2; ib = m + 2; }
            if (qb > qa) { qa = qb; ia = ib; }
            if (qa > best) { best = qa; bidx = ia; }
        }
        const bool fg = best >= 0.5f;
        const uint32_t pb = __float_as_uint(rand_pri[(size_t)b * K_TOT + k]);
        keys[(size_t)b * K_TOT + k] =
              (fg ? (1ull << 50) : 0ull)
            | ((uint64_t)pb << 20)
            | ((uint64_t)k  << 7)
            | (uint64_t)bidx;
    }
    __syncthreads();
    __threadfence();                            // make key stores device-visible
    if (tid == 0)
        __hip_atomic_fetch_add(&ctr[b], 1u, __ATOMIC_RELEASE, __HIP_MEMORY_SCOPE_AGENT);
    if (q != 0) return;                         // non-owner producers done

    // ---- owner: relaxed spin for all 4 producers, then one acquire fence ----
    if (tid == 0) {
        while (__hip_atomic_load(&ctr[b], __ATOMIC_RELAXED, __HIP_MEMORY_SCOPE_AGENT) < (uint32_t)QPI)
            __builtin_amdgcn_s_sleep(2);
    }
    __syncthreads();
    __builtin_amdgcn_fence(__ATOMIC_ACQUIRE, "agent");

    // ---- phase B: stage keys + histogram per group ----
    for (int i = tid; i < 512; i += NTH) s_hist[i >> 8][i & 255] = 0;
    if (tid < 2) s_cnt[tid] = 0;
    __syncthreads();
    for (int k = tid; k < K_TOT; k += NTH) {
        uint64_t key = keys[(size_t)b * K_TOT + k];
        s_keys[k] = key;
        int g = ((key >> 50) & 1ull) ? 0 : 1;   // 0 = fg, 1 = bg
        uint32_t pbits = (uint32_t)((key >> 20) & 0x3FFFFFFFull);
        int bucket = min(255, (int)(__uint_as_float(pbits) * 256.0f));  // monotone
        atomicAdd(&s_hist[g][bucket], 1);
    }
    __syncthreads();

    // Hillis-Steele suffix scan over each 256-bucket histogram
    for (int d = 1; d < 256; d <<= 1) {
        int v = 0, g = tid >> 8, t = tid & 255;
        bool act = (tid < 512) && (t + d < 256);
        if (act) v = s_hist[g][t + d];
        __syncthreads();
        if (act) s_hist[g][t] += v;
        __syncthreads();
    }

    if (tid == 0) {
        int fg_total = s_hist[0][0];
        int bg_total = s_hist[1][0];
        int nfg = min(NUM_FG_TGT, fg_total);
        int nbg = min(BATCH_PER - nfg, bg_total);
        s_needed[0] = nfg; s_needed[1] = nbg;
    }
    __syncthreads();

    // bucket threshold: max t with S[t] >= need (unique crossing; S non-increasing)
    if (tid < 512) {
        int g = tid >> 8, t = tid & 255;
        int need = s_needed[g];
        int St  = s_hist[g][t];
        int St1 = (t == 255) ? -1 : s_hist[g][t + 1];
        if (St >= need && St1 < need) s_T[g] = t;
    }
    if (tid < BATCH_PER) {                     // prefill invalid pattern
        s_out[0][tid] = 0.0f; s_out[1][tid] = -1.0f;
        s_out[2][tid] = -1.0f; s_out[3][tid] = -1.0f;
    }
    __syncthreads();

    const int nfg = s_needed[0], nbg = s_needed[1];
    if (tid < BATCH_PER)
        s_out[4][tid] = (tid < nfg + nbg) ? 1.0f : 0.0f;

    // compaction into disjoint halves (fg -> [0,HALF_CAP), bg -> [HALF_CAP,...))
    for (int k = tid; k < K_TOT; k += NTH) {
        uint64_t key = s_keys[k];
        int g = ((key >> 50) & 1ull) ? 0 : 1;
        uint32_t pbits = (uint32_t)((key >> 20) & 0x3FFFFFFFull);
        int bucket = min(255, (int)(__uint_as_float(pbits) * 256.0f));
        if (bucket >= s_T[g]) {
            int pos = atomicAdd(&s_cnt[g], 1);
            if (pos < HALF_CAP) s_cand[g * HALF_CAP + pos] = key;
        }
    }
    __syncthreads();

    // rank within each half (keys unique -> each slot written exactly once,
    // independent of atomic ordering) and emit
    const int fgc = min(s_cnt[0], HALF_CAP);
    const int bgc = min(s_cnt[1], HALF_CAP);
    for (int c = tid; c < fgc + bgc; c += NTH) {
        const bool isfg = (c < fgc);
        const int  base = isfg ? 0 : HALF_CAP;
        const int  cnt  = isfg ? fgc : bgc;
        const int  ci   = isfg ? c : (c - fgc);
        const uint64_t kc = s_cand[base + ci];
        int r = 0;
        for (int j = 0; j < cnt; ++j)          // broadcast LDS reads
            r += (s_cand[base + j] > kc) ? 1 : 0;
        int slot = -1;
        if (isfg) { if (r < nfg) slot = r; }
        else      { if (r < nbg) slot = nfg + r; }
        if (slot >= 0) {
            int idx = (int)((kc >> 7) & 0x1FFFull);
            int mi  = (int)(kc & 0x7Full);
            float bx1, by1, bx2, by2;
            if (idx < N_PROP) {
                const float4 bp = *(const float4*)(prop_boxes + ((size_t)b * N_PROP + idx) * 4);
                bx1 = bp.x; by1 = bp.y; bx2 = bp.z; by2 = bp.w;
            } else {
                const float4 bp = s_gtb4[idx - N_PROP];
                bx1 = bp.x; by1 = bp.y; bx2 = bp.z; by2 = bp.w;
            }
            float area_b;
            {
#pragma clang fp contract(off)
                area_b = (bx2 - bx1) * (by2 - by1);
            }
            // bit-exact matched_vals[idx]: same fp ops on same inputs as phase A
            float iou = iou_g(s_gtb4[mi], bx1, by1, bx2, by2, area_b);
            s_out[0][slot] = iou;
            s_out[1][slot] = (float)idx;
            s_out[2][slot] = (float)(isfg ? s_gtc[mi] : NUM_CLASSES_);
            s_out[3][slot] = (float)mi;
        }
    }
    __syncthreads();

    // coalesced write-out
    for (int i = tid; i < 5 * BATCH_PER; i += NTH) {
        int o = i / BATCH_PER, p = i % BATCH_PER;
        out[(size_t)o * OUT_STRIDE + (size_t)b * BATCH_PER + p] = s_out[o][p];
    }
}

// ---------------------------------------------------------------------------
// Fallback: proven single kernel (one block per image, zero workspace).
// Used only if ws_size is too small for the key buffer + counters.
// ---------------------------------------------------------------------------
__global__ __launch_bounds__(NTH) void roiheads_fallback(
        const float* __restrict__ gt_boxes,
        const float* __restrict__ prop_boxes,
        const int*   __restrict__ gt_classes,
        const float* __restrict__ rand_pri,
        float*       __restrict__ out)
{
    __shared__ uint64_t s_keys[K_TOT];
    __shared__ uint64_t s_cand[2 * HALF_CAP];
    __shared__ int      s_hist[2][256];
    __shared__ float4   s_gtb4[M_GT];
    __shared__ int      s_gtc[M_GT];
    __shared__ float    s_out[5][BATCH_PER];
    __shared__ int      s_T[2], s_needed[2], s_cnt[2];

    const int b   = blockIdx.x;
    const int tid = threadIdx.x;

    for (int i = tid; i < 512; i += NTH) s_hist[i >> 8][i & 255] = 0;
    if (tid < 2) s_cnt[tid] = 0;
    for (int i = tid; i < M_GT; i += NTH)
        s_gtb4[i] = ((const float4*)gt_boxes)[(size_t)b * M_GT + i];
    for (int i = tid; i < M_GT; i += NTH)
        s_gtc[i] = gt_classes[(size_t)b * M_GT + i];
    __syncthreads();

    for (int k = tid; k < K_TOT; k += NTH) {
        float bx1, by1, bx2, by2;
        if (k < N_PROP) {
            const float4 bp = *(const float4*)(prop_boxes + ((size_t)b * N_PROP + k) * 4);
            bx1 = bp.x; by1 = bp.y; bx2 = bp.z; by2 = bp.w;
        } else {
            const float4 bp = s_gtb4[k - N_PROP];
            bx1 = bp.x; by1 = bp.y; bx2 = bp.z; by2 = bp.w;
        }
        float area_b;
        {
#pragma clang fp contract(off)
            area_b = (bx2 - bx1) * (by2 - by1);
        }
        float best = -1.0f; int bidx = 0;
        for (int m = 0; m < M_GT; m += 4) {
            float4 g0 = s_gtb4[m + 0];
            float4 g1 = s_gtb4[m + 1];
            float4 g2 = s_gtb4[m + 2];
            float4 g3 = s_gtb4[m + 3];
            float q0 = iou_g(g0, bx1, by1, bx2, by2, area_b);
            float q1 = iou_g(g1, bx1, by1, bx2, by2, area_b);
            float q2 = iou_g(g2, bx1, by1, bx2, by2, area_b);
            float q3 = iou_g(g3, bx1, by1, bx2, by2, area_b);
            float qa; int ia;
            if (q1 > q0) { qa = q1; ia = m + 1; } else { qa = q0; ia = m; }
            float qb; int ib;
            if (q3 > q2) { qb = q3; ib = m + 3; } else { qb = q2; ib = m + 2; }
            if (qb > qa) { qa = qb; ia = ib; }
            if (qa > best) { best = qa; bidx = ia; }
        }
        const bool fg = best >= 0.5f;
        const float pri = rand_pri[(size_t)b * K_TOT + k];
        const uint32_t pb = __float_as_uint(pri);
        s_keys[k] = (fg ? (1ull << 50) : 0ull)
                  | ((uint64_t)pb << 20)
                  | ((uint64_t)k  << 7)
                  | (uint64_t)bidx;
        int bucket = min(255, (int)(pri * 256.0f));
        atomicAdd(&s_hist[fg ? 0 : 1][bucket], 1);
    }
    __syncthreads();

    for (int d = 1; d < 256; d <<= 1) {
        int v = 0, g = tid >> 8, t = tid & 255;
        bool act = (tid < 512) && (t + d < 256);
        if (act) v = s_hist[g][t + d];
        __syncthreads();
        if (act) s_hist[g][t] += v;
        __syncthreads();
    }

    if (tid == 0) {
        int fg_total = s_hist[0][0];
        int bg_total = s_hist[1][0];
        int nfg = min(NUM_FG_TGT, fg_total);
        int nbg = min(BATCH_PER - nfg, bg_total);
        s_needed[0] = nfg; s_needed[1] = nbg;
    }
    __syncthreads();

    if (tid < 512) {
        int g = tid >> 8, t = tid & 255;
        int need = s_needed[g];
        int St  = s_hist[g][t];
        int St1 = (t == 255) ? -1 : s_hist[g][t + 1];
        if (St >= need && St1 < need) s_T[g] = t;
    }
    if (tid < BATCH_PER) {
        s_out[0][tid] = 0.0f; s_out[1][tid] = -1.0f;
        s_out[2][tid] = -1.0f; s_out[3][tid] = -1.0f;
    }
    __syncthreads();

    const int nfg = s_needed[0], nbg = s_needed[1];
    if (tid < BATCH_PER)
        s_out[4][tid] = (tid < nfg + nbg) ? 1.0f : 0.0f;

    for (int k = tid; k < K_TOT; k += NTH) {
        uint64_t key = s_keys[k];
        int g = ((key >> 50) & 1ull) ? 0 : 1;
        uint32_t pbits = (uint32_t)((key >> 20) & 0x3FFFFFFFull);
        int bucket = min(255, (int)(__uint_as_float(pbits) * 256.0f));
        if (bucket >= s_T[g]) {
            int pos = atomicAdd(&s_cnt[g], 1);
            if (pos < HALF_CAP) s_cand[g * HALF_CAP + pos] = key;
        }
    }
    __syncthreads();

    const int fgc = min(s_cnt[0], HALF_CAP);
    const int bgc = min(s_cnt[1], HALF_CAP);
    for (int c = tid; c < fgc + bgc; c += NTH) {
        const bool isfg = (c < fgc);
        const int  base = isfg ? 0 : HALF_CAP;
        const int  cnt  = isfg ? fgc : bgc;
        const int  ci   = isfg ? c : (c - fgc);
        const uint64_t kc = s_cand[base + ci];
        int r = 0;
        for (int j = 0; j < cnt; ++j)
            r += (s_cand[base + j] > kc) ? 1 : 0;
        int slot = -1;
        if (isfg) { if (r < nfg) slot = r; }
        else      { if (r < nbg) slot = nfg + r; }
        if (slot >= 0) {
            int idx = (int)((kc >> 7) & 0x1FFFull);
            int mi  = (int)(kc & 0x7Full);
            float bx1, by1, bx2, by2;
            if (idx < N_PROP) {
                const float4 bp = *(const float4*)(prop_boxes + ((size_t)b * N_PROP + idx) * 4);
                bx1 = bp.x; by1 = bp.y; bx2 = bp.z; by2 = bp.w;
            } else {
                const float4 bp = s_gtb4[idx - N_PROP];
                bx1 = bp.x; by1 = bp.y; bx2 = bp.z; by2 = bp.w;
            }
            float area_b;
            {
#pragma clang fp contract(off)
                area_b = (bx2 - bx1) * (by2 - by1);
            }
            float iou = iou_g(s_gtb4[mi], bx1, by1, bx2, by2, area_b);
            s_out[0][slot] = iou;
            s_out[1][slot] = (float)idx;
            s_out[2][slot] = (float)(isfg ? s_gtc[mi] : NUM_CLASSES_);
            s_out[3][slot] = (float)mi;
        }
    }
    __syncthreads();

    for (int i = tid; i < 5 * BATCH_PER; i += NTH) {
        int o = i / BATCH_PER, p = i % BATCH_PER;
        out[(size_t)o * OUT_STRIDE + (size_t)b * BATCH_PER + p] = s_out[o][p];
    }
}

extern "C" void kernel_launch(void* const* d_in, const int* in_sizes, int n_in,
                              void* d_out, int out_size, void* d_ws, size_t ws_size,
                              hipStream_t stream) {
    const float* gt_boxes   = (const float*)d_in[0];  // [64,100,4]
    const float* prop_boxes = (const float*)d_in[1];  // [64,4000,4]
    const int*   gt_classes = (const int*)  d_in[2];  // [64,100]
    const float* rand_pri   = (const float*)d_in[3];  // [64,4100]
    float* out = (float*)d_out;                       // 5 x [64,512] float32, concat

    const size_t need_ws = CTR_BYTES + (size_t)B_IMG * K_TOT * sizeof(uint64_t);
    if (d_ws != nullptr && ws_size >= need_ws) {
        uint32_t* ctr  = (uint32_t*)d_ws;
        uint64_t* keys = (uint64_t*)((char*)d_ws + CTR_BYTES);
        // zero arrival counters (captured into the graph, ordered on stream)
        hipMemsetAsync(d_ws, 0, CTR_BYTES, stream);
        fused_kernel<<<B_IMG * QPI, NTH, 0, stream>>>(gt_boxes, prop_boxes,
                                                      gt_classes, rand_pri,
                                                      keys, ctr, out);
    } else {
        roiheads_fallback<<<B_IMG, NTH, 0, stream>>>(gt_boxes, prop_boxes,
                                                     gt_classes, rand_pri, out);
    }
}

// Round 8
// 177.024 us; speedup vs baseline: 1.1210x; 1.0704x over previous
//
#include <hip/hip_runtime.h>
#include <stdint.h>

// Problem constants (fixed by the reference)
#define B_IMG        64
#define M_GT         100
#define N_PROP       4000
#define K_TOT        4100          // N + M (proposal_append_gt)
#define NUM_CLASSES_ 80
#define BATCH_PER    512
#define NUM_FG_TGT   128
#define OUT_STRIDE   (B_IMG * BATCH_PER)   // 32768 elements per output tensor

#define NT           256                   // threads per block (fused kernel)
#define KTILE        4                     // independent proposal chains/thread
#define HALF_CAP     1024                  // candidate capacity per group (fg | bg)
#define QPI          4                     // producer blocks (quarters) per image
#define QLEN         1025                  // ceil(K_TOT / QPI)
#define CTR_BYTES    1024                  // arrival-counter region at front of ws
#define NTF          1024                  // threads per block (fallback kernel)

// Key packing (uint64 compare gives exact (fg, pri, idx) descending order;
// midx rides in the low bits — idx is unique so it never affects ordering):
//   bit 50      : fg flag
//   bits 49..20 : float bits of priority (pri in [0,1) => bits < 2^30)
//   bits 19..7  : element index (0..4099 < 8192)  — reproduces the reversed-
//                 stable-argsort tiebreak (higher idx first on equal pri)
//   bits  6..0  : matched gt index (0..99 < 128)

// IoU with contraction disabled so float32 results match the numpy reference
// bit-for-bit. area_a computed in-register with the identical expression.
__device__ __forceinline__ float iou_g(float4 g,
                                       float bx1, float by1, float bx2, float by2,
                                       float area_b) {
#pragma clang fp contract(off)
    float area_a = (g.z - g.x) * (g.w - g.y);
    float ltx = fmaxf(g.x, bx1), lty = fmaxf(g.y, by1);
    float rbx = fminf(g.z, bx2), rby = fminf(g.w, by2);
    float wx = fmaxf(rbx - ltx, 0.0f);
    float wy = fmaxf(rby - lty, 0.0f);
    float inter = wx * wy;
    float uni = area_a + area_b - inter;
    return inter > 0.0f ? inter / uni : 0.0f;
}

// ---------------------------------------------------------------------------
// Fused chip-wide kernel. Grid = B_IMG*QPI = 256 blocks x 256 threads.
// Block blk: image b = blk>>2, quarter q = blk&3.
//   Phase A: each thread runs KTILE=4 INDEPENDENT IoU-argmax chains (k-axis
//            tiling) -> true ILP: per m-iteration one broadcast LDS read of
//            the gt box feeds 4 independent div/compare chains. Each chain is
//            sequential over m => exact first-occurrence argmax per element.
//   Handoff: __syncthreads + __threadfence + release-add on ctr[b]; owner
//            (q==0) relaxed-spins, then one block-wide acquire fence.
//   Phase B (64 owners): stage keys + histogram, suffix-scan, threshold,
//            compact, O(k^2)-broadcast rank, emit.
// Deadlock-free: LDS ~63.5KB => 2 blocks/CU; __launch_bounds__(256,4) =>
// VGPR<=128 => 4 waves/block fits 4x/CU; grid 256 <= capacity: co-resident.
// ---------------------------------------------------------------------------
__global__ __launch_bounds__(NT, 4) void fused_kernel(
        const float* __restrict__ gt_boxes,    // [B, M, 4]
        const float* __restrict__ prop_boxes,  // [B, N, 4]
        const int*   __restrict__ gt_classes,  // [B, M]
        const float* __restrict__ rand_pri,    // [B, K]
        uint64_t*    __restrict__ keys,        // [B, K] in ws (after ctr region)
        uint32_t*    __restrict__ ctr,         // [B] arrival counters (zeroed)
        float*       __restrict__ out)         // 5 x [B, 512] flat
{
    __shared__ uint64_t s_keys[K_TOT];         // 32.8 KB (owner phase B)
    __shared__ uint64_t s_cand[2 * HALF_CAP];  // 16 KB: fg half | bg half
    __shared__ int      s_hist[2][256];        // 2 KB
    __shared__ float4   s_gtb4[M_GT];          // 1.6 KB gt boxes as float4
    __shared__ int      s_gtc[M_GT];
    __shared__ float    s_out[5][BATCH_PER];   // 10 KB staging
    __shared__ int      s_T[2], s_needed[2], s_cnt[2];

    const int blk = blockIdx.x;
    const int b   = blk >> 2;
    const int q   = blk & 3;
    const int tid = threadIdx.x;

    // ---- stage gt data for image b ----
    for (int i = tid; i < M_GT; i += NT)
        s_gtb4[i] = ((const float4*)gt_boxes)[(size_t)b * M_GT + i];
    for (int i = tid; i < M_GT; i += NT)
        s_gtc[i] = gt_classes[(size_t)b * M_GT + i];
    __syncthreads();

    // ---- phase A: KTILE independent IoU-argmax chains per thread ----
    const int qstart = q * QLEN;
    const int qend   = min(qstart + QLEN, K_TOT);
    for (int kb = qstart + tid; kb < qend; kb += KTILE * NT) {
        int   kk[KTILE];
        bool  val[KTILE];
        float x1[KTILE], y1[KTILE], x2[KTILE], y2[KTILE], ab[KTILE], best[KTILE];
        int   bidx[KTILE];
#pragma unroll
        for (int j = 0; j < KTILE; ++j) {
            kk[j]  = kb + j * NT;
            val[j] = kk[j] < qend;
            const int ks = val[j] ? kk[j] : qstart;    // safe address
            float4 bp;
            if (ks < N_PROP)
                bp = *(const float4*)(prop_boxes + ((size_t)b * N_PROP + ks) * 4);
            else
                bp = s_gtb4[ks - N_PROP];
            x1[j] = bp.x; y1[j] = bp.y; x2[j] = bp.z; y2[j] = bp.w;
            {
#pragma clang fp contract(off)
                ab[j] = (x2[j] - x1[j]) * (y2[j] - y1[j]);
            }
            best[j] = -1.0f; bidx[j] = 0;
        }
        for (int m = 0; m < M_GT; ++m) {
            const float4 g = s_gtb4[m];                // broadcast LDS read
#pragma unroll
            for (int j = 0; j < KTILE; ++j) {
                float iv = iou_g(g, x1[j], y1[j], x2[j], y2[j], ab[j]);
                if (iv > best[j]) { best[j] = iv; bidx[j] = m; }  // strict >
            }
        }
#pragma unroll
        for (int j = 0; j < KTILE; ++j) {
            if (!val[j]) continue;
            const bool fg = best[j] >= 0.5f;
            const uint32_t pb = __float_as_uint(rand_pri[(size_t)b * K_TOT + kk[j]]);
            keys[(size_t)b * K_TOT + kk[j]] =
                  (fg ? (1ull << 50) : 0ull)
                | ((uint64_t)pb << 20)
                | ((uint64_t)kk[j] << 7)
                | (uint64_t)bidx[j];
        }
    }
    __syncthreads();
    __threadfence();                            // make key stores device-visible
    if (tid == 0)
        __hip_atomic_fetch_add(&ctr[b], 1u, __ATOMIC_RELEASE, __HIP_MEMORY_SCOPE_AGENT);
    if (q != 0) return;                         // non-owner producers done

    // ---- owner: relaxed spin for all 4 producers, then one acquire fence ----
    if (tid == 0) {
        while (__hip_atomic_load(&ctr[b], __ATOMIC_RELAXED, __HIP_MEMORY_SCOPE_AGENT) < (uint32_t)QPI)
            __builtin_amdgcn_s_sleep(2);
    }
    __syncthreads();
    __builtin_amdgcn_fence(__ATOMIC_ACQUIRE, "agent");

    // ---- phase B: stage keys + histogram per group ----
    for (int i = tid; i < 512; i += NT) s_hist[i >> 8][i & 255] = 0;
    if (tid < 2) s_cnt[tid] = 0;
    __syncthreads();
    for (int k = tid; k < K_TOT; k += NT) {
        uint64_t key = keys[(size_t)b * K_TOT + k];
        s_keys[k] = key;
        int g = ((key >> 50) & 1ull) ? 0 : 1;   // 0 = fg, 1 = bg
        uint32_t pbits = (uint32_t)((key >> 20) & 0x3FFFFFFFull);
        int bucket = min(255, (int)(__uint_as_float(pbits) * 256.0f));  // monotone
        atomicAdd(&s_hist[g][bucket], 1);
    }
    __syncthreads();

    // Hillis-Steele suffix scan over both 256-bucket histograms (NT=256:
    // each thread handles bucket tid of fg and of bg per step)
    for (int d = 1; d < 256; d <<= 1) {
        int v0 = 0, v1 = 0;
        const bool act = (tid + d < 256);
        if (act) { v0 = s_hist[0][tid + d]; v1 = s_hist[1][tid + d]; }
        __syncthreads();
        if (act) { s_hist[0][tid] += v0; s_hist[1][tid] += v1; }
        __syncthreads();
    }

    if (tid == 0) {
        int fg_total = s_hist[0][0];
        int bg_total = s_hist[1][0];
        int nfg = min(NUM_FG_TGT, fg_total);
        int nbg = min(BATCH_PER - nfg, bg_total);
        s_needed[0] = nfg; s_needed[1] = nbg;
    }
    __syncthreads();

    // bucket threshold: max t with S[t] >= need (unique crossing; S non-increasing)
    {
        const int t = tid;
#pragma unroll
        for (int g = 0; g < 2; ++g) {
            int need = s_needed[g];
            int St  = s_hist[g][t];
            int St1 = (t == 255) ? -1 : s_hist[g][t + 1];
            if (St >= need && St1 < need) s_T[g] = t;
        }
    }
    // prefill output staging with the invalid pattern
    for (int i = tid; i < BATCH_PER; i += NT) {
        s_out[0][i] = 0.0f; s_out[1][i] = -1.0f;
        s_out[2][i] = -1.0f; s_out[3][i] = -1.0f;
    }
    __syncthreads();

    const int nfg = s_needed[0], nbg = s_needed[1];
    for (int i = tid; i < BATCH_PER; i += NT)
        s_out[4][i] = (i < nfg + nbg) ? 1.0f : 0.0f;

    // compaction into disjoint halves (fg -> [0,HALF_CAP), bg -> [HALF_CAP,...))
    for (int k = tid; k < K_TOT; k += NT) {
        uint64_t key = s_keys[k];
        int g = ((key >> 50) & 1ull) ? 0 : 1;
        uint32_t pbits = (uint32_t)((key >> 20) & 0x3FFFFFFFull);
        int bucket = min(255, (int)(__uint_as_float(pbits) * 256.0f));
        if (bucket >= s_T[g]) {
            int pos = atomicAdd(&s_cnt[g], 1);
            if (pos < HALF_CAP) s_cand[g * HALF_CAP + pos] = key;
        }
    }
    __syncthreads();

    // rank within each half (keys unique -> each slot written exactly once,
    // independent of atomic ordering) and emit
    const int fgc = min(s_cnt[0], HALF_CAP);
    const int bgc = min(s_cnt[1], HALF_CAP);
    for (int c = tid; c < fgc + bgc; c += NT) {
        const bool isfg = (c < fgc);
        const int  base = isfg ? 0 : HALF_CAP;
        const int  cnt  = isfg ? fgc : bgc;
        const int  ci   = isfg ? c : (c - fgc);
        const uint64_t kc = s_cand[base + ci];
        int r = 0;
        for (int j = 0; j < cnt; ++j)           // broadcast LDS reads
            r += (s_cand[base + j] > kc) ? 1 : 0;
        int slot = -1;
        if (isfg) { if (r < nfg) slot = r; }
        else      { if (r < nbg) slot = nfg + r; }
        if (slot >= 0) {
            int idx = (int)((kc >> 7) & 0x1FFFull);
            int mi  = (int)(kc & 0x7Full);
            float bx1, by1, bx2, by2;
            if (idx < N_PROP) {
                const float4 bp = *(const float4*)(prop_boxes + ((size_t)b * N_PROP + idx) * 4);
                bx1 = bp.x; by1 = bp.y; bx2 = bp.z; by2 = bp.w;
            } else {
                const float4 bp = s_gtb4[idx - N_PROP];
                bx1 = bp.x; by1 = bp.y; bx2 = bp.z; by2 = bp.w;
            }
            float area_b;
            {
#pragma clang fp contract(off)
                area_b = (bx2 - bx1) * (by2 - by1);
            }
            // bit-exact matched_vals[idx]: same fp ops on same inputs as phase A
            float iou = iou_g(s_gtb4[mi], bx1, by1, bx2, by2, area_b);
            s_out[0][slot] = iou;
            s_out[1][slot] = (float)idx;
            s_out[2][slot] = (float)(isfg ? s_gtc[mi] : NUM_CLASSES_);
            s_out[3][slot] = (float)mi;
        }
    }
    __syncthreads();

    // coalesced write-out
    for (int i = tid; i < 5 * BATCH_PER; i += NT) {
        int o = i / BATCH_PER, p = i % BATCH_PER;
        out[(size_t)o * OUT_STRIDE + (size_t)b * BATCH_PER + p] = s_out[o][p];
    }
}

// ---------------------------------------------------------------------------
// Fallback: proven single kernel (one block per image, zero workspace).
// Used only if ws_size is too small for the key buffer + counters.
// ---------------------------------------------------------------------------
__global__ __launch_bounds__(NTF) void roiheads_fallback(
        const float* __restrict__ gt_boxes,
        const float* __restrict__ prop_boxes,
        const int*   __restrict__ gt_classes,
        const float* __restrict__ rand_pri,
        float*       __restrict__ out)
{
    __shared__ uint64_t s_keys[K_TOT];
    __shared__ uint64_t s_cand[2 * HALF_CAP];
    __shared__ int      s_hist[2][256];
    __shared__ float4   s_gtb4[M_GT];
    __shared__ int      s_gtc[M_GT];
    __shared__ float    s_out[5][BATCH_PER];
    __shared__ int      s_T[2], s_needed[2], s_cnt[2];

    const int b   = blockIdx.x;
    const int tid = threadIdx.x;

    for (int i = tid; i < 512; i += NTF) s_hist[i >> 8][i & 255] = 0;
    if (tid < 2) s_cnt[tid] = 0;
    for (int i = tid; i < M_GT; i += NTF)
        s_gtb4[i] = ((const float4*)gt_boxes)[(size_t)b * M_GT + i];
    for (int i = tid; i < M_GT; i += NTF)
        s_gtc[i] = gt_classes[(size_t)b * M_GT + i];
    __syncthreads();

    for (int k = tid; k < K_TOT; k += NTF) {
        float bx1, by1, bx2, by2;
        if (k < N_PROP) {
            const float4 bp = *(const float4*)(prop_boxes + ((size_t)b * N_PROP + k) * 4);
            bx1 = bp.x; by1 = bp.y; bx2 = bp.z; by2 = bp.w;
        } else {
            const float4 bp = s_gtb4[k - N_PROP];
            bx1 = bp.x; by1 = bp.y; bx2 = bp.z; by2 = bp.w;
        }
        float area_b;
        {
#pragma clang fp contract(off)
            area_b = (bx2 - bx1) * (by2 - by1);
        }
        float best = -1.0f; int bidx = 0;
        for (int m = 0; m < M_GT; ++m) {
            float iv = iou_g(s_gtb4[m], bx1, by1, bx2, by2, area_b);
            if (iv > best) { best = iv; bidx = m; }
        }
        const bool fg = best >= 0.5f;
        const float pri = rand_pri[(size_t)b * K_TOT + k];
        const uint32_t pb = __float_as_uint(pri);
        s_keys[k] = (fg ? (1ull << 50) : 0ull)
                  | ((uint64_t)pb << 20)
                  | ((uint64_t)k  << 7)
                  | (uint64_t)bidx;
        int bucket = min(255, (int)(pri * 256.0f));
        atomicAdd(&s_hist[fg ? 0 : 1][bucket], 1);
    }
    __syncthreads();

    for (int d = 1; d < 256; d <<= 1) {
        int v = 0, g = tid >> 8, t = tid & 255;
        bool act = (tid < 512) && (t + d < 256);
        if (act) v = s_hist[g][t + d];
        __syncthreads();
        if (act) s_hist[g][t] += v;
        __syncthreads();
    }

    if (tid == 0) {
        int fg_total = s_hist[0][0];
        int bg_total = s_hist[1][0];
        int nfg = min(NUM_FG_TGT, fg_total);
        int nbg = min(BATCH_PER - nfg, bg_total);
        s_needed[0] = nfg; s_needed[1] = nbg;
    }
    __syncthreads();

    if (tid < 512) {
        int g = tid >> 8, t = tid & 255;
        int need = s_needed[g];
        int St  = s_hist[g][t];
        int St1 = (t == 255) ? -1 : s_hist[g][t + 1];
        if (St >= need && St1 < need) s_T[g] = t;
    }
    if (tid < BATCH_PER) {
        s_out[0][tid] = 0.0f; s_out[1][tid] = -1.0f;
        s_out[2][tid] = -1.0f; s_out[3][tid] = -1.0f;
    }
    __syncthreads();

    const int nfg = s_needed[0], nbg = s_needed[1];
    if (tid < BATCH_PER)
        s_out[4][tid] = (tid < nfg + nbg) ? 1.0f : 0.0f;

    for (int k = tid; k < K_TOT; k += NTF) {
        uint64_t key = s_keys[k];
        int g = ((key >> 50) & 1ull) ? 0 : 1;
        uint32_t pbits = (uint32_t)((key >> 20) & 0x3FFFFFFFull);
        int bucket = min(255, (int)(__uint_as_float(pbits) * 256.0f));
        if (bucket >= s_T[g]) {
            int pos = atomicAdd(&s_cnt[g], 1);
            if (pos < HALF_CAP) s_cand[g * HALF_CAP + pos] = key;
        }
    }
    __syncthreads();

    const int fgc = min(s_cnt[0], HALF_CAP);
    const int bgc = min(s_cnt[1], HALF_CAP);
    for (int c = tid; c < fgc + bgc; c += NTF) {
        const bool isfg = (c < fgc);
        const int  base = isfg ? 0 : HALF_CAP;
        const int  cnt  = isfg ? fgc : bgc;
        const int  ci   = isfg ? c : (c - fgc);
        const uint64_t kc = s_cand[base + ci];
        int r = 0;
        for (int j = 0; j < cnt; ++j)
            r += (s_cand[base + j] > kc) ? 1 : 0;
        int slot = -1;
        if (isfg) { if (r < nfg) slot = r; }
        else      { if (r < nbg) slot = nfg + r; }
        if (slot >= 0) {
            int idx = (int)((kc >> 7) & 0x1FFFull);
            int mi  = (int)(kc & 0x7Full);
            float bx1, by1, bx2, by2;
            if (idx < N_PROP) {
                const float4 bp = *(const float4*)(prop_boxes + ((size_t)b * N_PROP + idx) * 4);
                bx1 = bp.x; by1 = bp.y; bx2 = bp.z; by2 = bp.w;
            } else {
                const float4 bp = s_gtb4[idx - N_PROP];
                bx1 = bp.x; by1 = bp.y; bx2 = bp.z; by2 = bp.w;
            }
            float area_b;
            {
#pragma clang fp contract(off)
                area_b = (bx2 - bx1) * (by2 - by1);
            }
            float iou = iou_g(s_gtb4[mi], bx1, by1, bx2, by2, area_b);
            s_out[0][slot] = iou;
            s_out[1][slot] = (float)idx;
            s_out[2][slot] = (float)(isfg ? s_gtc[mi] : NUM_CLASSES_);
            s_out[3][slot] = (float)mi;
        }
    }
    __syncthreads();

    for (int i = tid; i < 5 * BATCH_PER; i += NTF) {
        int o = i / BATCH_PER, p = i % BATCH_PER;
        out[(size_t)o * OUT_STRIDE + (size_t)b * BATCH_PER + p] = s_out[o][p];
    }
}

extern "C" void kernel_launch(void* const* d_in, const int* in_sizes, int n_in,
                              void* d_out, int out_size, void* d_ws, size_t ws_size,
                              hipStream_t stream) {
    const float* gt_boxes   = (const float*)d_in[0];  // [64,100,4]
    const float* prop_boxes = (const float*)d_in[1];  // [64,4000,4]
    const int*   gt_classes = (const int*)  d_in[2];  // [64,100]
    const float* rand_pri   = (const float*)d_in[3];  // [64,4100]
    float* out = (float*)d_out;                       // 5 x [64,512] float32, concat

    const size_t need_ws = CTR_BYTES + (size_t)B_IMG * K_TOT * sizeof(uint64_t);
    if (d_ws != nullptr && ws_size >= need_ws) {
        uint32_t* ctr  = (uint32_t*)d_ws;
        uint64_t* keys = (uint64_t*)((char*)d_ws + CTR_BYTES);
        // zero arrival counters (captured into the graph, ordered on stream)
        hipMemsetAsync(d_ws, 0, CTR_BYTES, stream);
        fused_kernel<<<B_IMG * QPI, NT, 0, stream>>>(gt_boxes, prop_boxes,
                                                     gt_classes, rand_pri,
                                                     keys, ctr, out);
    } else {
        roiheads_fallback<<<B_IMG, NTF, 0, stream>>>(gt_boxes, prop_boxes,
                                                     gt_classes, rand_pri, out);
    }
}

// Round 9
// 131.900 us; speedup vs baseline: 1.5045x; 1.3421x over previous
//
#include <hip/hip_runtime.h>
#include <stdint.h>

// Problem constants (fixed by the reference)
#define B_IMG        64
#define M_GT         100
#define N_PROP       4000
#define K_TOT        4100          // N + M (proposal_append_gt)
#define NUM_CLASSES_ 80
#define BATCH_PER    512
#define NUM_FG_TGT   128
#define OUT_STRIDE   (B_IMG * BATCH_PER)   // 32768 elements per output tensor

#define NTH          1024                  // threads per block
#define HALF_CAP     1024                  // candidate capacity per group (fg | bg)
#define QPI          4                     // producer blocks (quarters) per image
#define QLEN         1025                  // K_TOT / QPI
#define CTR_BYTES    1024                  // arrival-counter region at front of ws

// Key packing (uint64 compare gives exact (fg, pri, idx) descending order;
// midx rides in the low bits — idx is unique so it never affects ordering):
//   bit 50      : fg flag
//   bits 49..20 : float bits of priority (pri in [0,1) => bits < 2^30)
//   bits 19..7  : element index (0..4099 < 8192)  — reproduces the reversed-
//                 stable-argsort tiebreak (higher idx first on equal pri)
//   bits  6..0  : matched gt index (0..99 < 128)

// IoU with contraction disabled so float32 results match the numpy reference
// bit-for-bit. area_a computed in-register with the identical expression as
// the reference's precomputed area (same inputs, same op order => same bits).
__device__ __forceinline__ float iou_g(float4 g,
                                       float bx1, float by1, float bx2, float by2,
                                       float area_b) {
#pragma clang fp contract(off)
    float area_a = (g.z - g.x) * (g.w - g.y);
    float ltx = fmaxf(g.x, bx1), lty = fmaxf(g.y, by1);
    float rbx = fminf(g.z, bx2), rby = fminf(g.w, by2);
    float wx = fmaxf(rbx - ltx, 0.0f);
    float wy = fmaxf(rby - lty, 0.0f);
    float inter = wx * wy;
    float uni = area_a + area_b - inter;
    return inter > 0.0f ? inter / uni : 0.0f;
}

// ---------------------------------------------------------------------------
// Fused chip-wide kernel (R5 skeleton, 105 us baseline). Two changes:
//  (a) keys are transported producer->owner via AGENT-scope relaxed atomic
//      stores/loads (coherent, L2-bypassing) so the release/acquire handoff
//      has no dirty non-coherent L2 data to drain — attacks the hidden
//      ~60-80 us that R5-R8 all paid regardless of phase-A speed;
//  (b) gt boxes staged as float4 (one ds_read_b128 per m instead of five
//      ds_read_b32) and rand_pri hoisted above the m-loop.
// Grid = B_IMG*QPI = 256 blocks x 1024 threads. b = blk>>2, q = blk&3.
// Deadlock-free: all 256 blocks fit co-resident (<=64KB LDS => >=2 blocks/CU
// capacity on 256 CUs); no dispatch-order assumption.
// ---------------------------------------------------------------------------
__global__ __launch_bounds__(NTH, 8) void fused_kernel(
        const float* __restrict__ gt_boxes,    // [B, M, 4]
        const float* __restrict__ prop_boxes,  // [B, N, 4]
        const int*   __restrict__ gt_classes,  // [B, M]
        const float* __restrict__ rand_pri,    // [B, K]
        uint64_t*    __restrict__ keys,        // [B, K] in ws (after ctr region)
        uint32_t*    __restrict__ ctr,         // [B] arrival counters (zeroed)
        float*       __restrict__ out)         // 5 x [B, 512] flat
{
    __shared__ uint64_t s_keys[K_TOT];         // 32.8 KB (owner phase B)
    __shared__ uint64_t s_cand[2 * HALF_CAP];  // 16 KB: fg half | bg half
    __shared__ int      s_hist[2][256];        // 2 KB
    __shared__ float4   s_gtb4[M_GT];          // 1.6 KB gt boxes as float4
    __shared__ int      s_gtc[M_GT];
    __shared__ float    s_out[5][BATCH_PER];   // 10 KB staging
    __shared__ int      s_T[2], s_needed[2], s_cnt[2];

    const int blk = blockIdx.x;
    const int b   = blk >> 2;
    const int q   = blk & 3;
    const int tid = threadIdx.x;

    // ---- stage gt data for image b ----
    for (int i = tid; i < M_GT; i += NTH)
        s_gtb4[i] = ((const float4*)gt_boxes)[(size_t)b * M_GT + i];
    for (int i = tid; i < M_GT; i += NTH)
        s_gtc[i] = gt_classes[(size_t)b * M_GT + i];
    __syncthreads();

    // ---- phase A: IoU argmax + key build for quarter q ----
    for (int t = tid; t < QLEN; t += NTH) {
        const int k = q * QLEN + t;            // 4*1025 == 4100: always < K_TOT
        // hoisted global loads (overlap HBM latency with the m-loop)
        const uint32_t pb = __float_as_uint(rand_pri[(size_t)b * K_TOT + k]);
        float bx1, by1, bx2, by2;
        if (k < N_PROP) {
            const float4 bp = *(const float4*)(prop_boxes + ((size_t)b * N_PROP + k) * 4);
            bx1 = bp.x; by1 = bp.y; bx2 = bp.z; by2 = bp.w;
        } else {
            const float4 bp = s_gtb4[k - N_PROP];
            bx1 = bp.x; by1 = bp.y; bx2 = bp.z; by2 = bp.w;
        }
        float area_b;
        {
#pragma clang fp contract(off)
            area_b = (bx2 - bx1) * (by2 - by1);
        }
        float best = -1.0f; int bidx = 0;
        for (int m = 0; m < M_GT; ++m) {
            float iv = iou_g(s_gtb4[m], bx1, by1, bx2, by2, area_b);  // 1 ds_read_b128
            if (iv > best) { best = iv; bidx = m; }   // strict > => first-occurrence argmax
        }
        const bool fg = best >= 0.5f;
        uint64_t key = (fg ? (1ull << 50) : 0ull)
                     | ((uint64_t)pb << 20)
                     | ((uint64_t)k  << 7)
                     | (uint64_t)bidx;
        // coherent (L2-bypassing) store: nothing dirty left for the release
        __hip_atomic_store(&keys[(size_t)b * K_TOT + k], key,
                           __ATOMIC_RELAXED, __HIP_MEMORY_SCOPE_AGENT);
    }
    __syncthreads();
    if (tid == 0)    // release orders the atomic key stores before the arrival
        __hip_atomic_fetch_add(&ctr[b], 1u, __ATOMIC_RELEASE, __HIP_MEMORY_SCOPE_AGENT);
    if (q != 0) return;                         // non-owner producers done

    // ---- owner: relaxed spin for all 4 producers, then one acquire fence ----
    if (tid == 0) {
        while (__hip_atomic_load(&ctr[b], __ATOMIC_RELAXED, __HIP_MEMORY_SCOPE_AGENT) < (uint32_t)QPI)
            __builtin_amdgcn_s_sleep(2);
    }
    __syncthreads();
    __builtin_amdgcn_fence(__ATOMIC_ACQUIRE, "agent");

    // ---- phase B: stage keys + histogram per group ----
    for (int i = tid; i < 512; i += NTH) s_hist[i >> 8][i & 255] = 0;
    if (tid < 2) s_cnt[tid] = 0;
    __syncthreads();
    for (int k = tid; k < K_TOT; k += NTH) {
        uint64_t key = __hip_atomic_load(&keys[(size_t)b * K_TOT + k],
                                         __ATOMIC_RELAXED, __HIP_MEMORY_SCOPE_AGENT);
        s_keys[k] = key;
        int g = ((key >> 50) & 1ull) ? 0 : 1;   // 0 = fg, 1 = bg
        uint32_t pbits = (uint32_t)((key >> 20) & 0x3FFFFFFFull);
        int bucket = min(255, (int)(__uint_as_float(pbits) * 256.0f));  // monotone
        atomicAdd(&s_hist[g][bucket], 1);
    }
    __syncthreads();

    // Hillis-Steele suffix scan over each 256-bucket histogram
    for (int d = 1; d < 256; d <<= 1) {
        int v = 0, g = tid >> 8, t = tid & 255;
        bool act = (tid < 512) && (t + d < 256);
        if (act) v = s_hist[g][t + d];
        __syncthreads();
        if (act) s_hist[g][t] += v;
        __syncthreads();
    }

    if (tid == 0) {
        int fg_total = s_hist[0][0];
        int bg_total = s_hist[1][0];
        int nfg = min(NUM_FG_TGT, fg_total);
        int nbg = min(BATCH_PER - nfg, bg_total);
        s_needed[0] = nfg; s_needed[1] = nbg;
    }
    __syncthreads();

    // bucket threshold: max t with S[t] >= need (unique crossing; S non-increasing)
    if (tid < 512) {
        int g = tid >> 8, t = tid & 255;
        int need = s_needed[g];
        int St  = s_hist[g][t];
        int St1 = (t == 255) ? -1 : s_hist[g][t + 1];
        if (St >= need && St1 < need) s_T[g] = t;
    }
    if (tid < BATCH_PER) {                     // prefill invalid pattern
        s_out[0][tid] = 0.0f; s_out[1][tid] = -1.0f;
        s_out[2][tid] = -1.0f; s_out[3][tid] = -1.0f;
    }
    __syncthreads();

    const int nfg = s_needed[0], nbg = s_needed[1];
    if (tid < BATCH_PER)
        s_out[4][tid] = (tid < nfg + nbg) ? 1.0f : 0.0f;

    // compaction into disjoint halves (fg -> [0,HALF_CAP), bg -> [HALF_CAP,...))
    for (int k = tid; k < K_TOT; k += NTH) {
        uint64_t key = s_keys[k];
        int g = ((key >> 50) & 1ull) ? 0 : 1;
        uint32_t pbits = (uint32_t)((key >> 20) & 0x3FFFFFFFull);
        int bucket = min(255, (int)(__uint_as_float(pbits) * 256.0f));
        if (bucket >= s_T[g]) {
            int pos = atomicAdd(&s_cnt[g], 1);
            if (pos < HALF_CAP) s_cand[g * HALF_CAP + pos] = key;
        }
    }
    __syncthreads();

    // rank within each half (keys unique -> each slot written exactly once,
    // independent of atomic ordering) and emit
    const int fgc = min(s_cnt[0], HALF_CAP);
    const int bgc = min(s_cnt[1], HALF_CAP);
    for (int c = tid; c < fgc + bgc; c += NTH) {
        const bool isfg = (c < fgc);
        const int  base = isfg ? 0 : HALF_CAP;
        const int  cnt  = isfg ? fgc : bgc;
        const int  ci   = isfg ? c : (c - fgc);
        const uint64_t kc = s_cand[base + ci];
        int r = 0;
        for (int j = 0; j < cnt; ++j)          // broadcast LDS reads
            r += (s_cand[base + j] > kc) ? 1 : 0;
        int slot = -1;
        if (isfg) { if (r < nfg) slot = r; }
        else      { if (r < nbg) slot = nfg + r; }
        if (slot >= 0) {
            int idx = (int)((kc >> 7) & 0x1FFFull);
            int mi  = (int)(kc & 0x7Full);
            float bx1, by1, bx2, by2;
            if (idx < N_PROP) {
                const float4 bp = *(const float4*)(prop_boxes + ((size_t)b * N_PROP + idx) * 4);
                bx1 = bp.x; by1 = bp.y; bx2 = bp.z; by2 = bp.w;
            } else {
                const float4 bp = s_gtb4[idx - N_PROP];
                bx1 = bp.x; by1 = bp.y; bx2 = bp.z; by2 = bp.w;
            }
            float area_b;
            {
#pragma clang fp contract(off)
                area_b = (bx2 - bx1) * (by2 - by1);
            }
            // bit-exact matched_vals[idx]: same fp ops on same inputs as phase A
            float iou = iou_g(s_gtb4[mi], bx1, by1, bx2, by2, area_b);
            s_out[0][slot] = iou;
            s_out[1][slot] = (float)idx;
            s_out[2][slot] = (float)(isfg ? s_gtc[mi] : NUM_CLASSES_);
            s_out[3][slot] = (float)mi;
        }
    }
    __syncthreads();

    // coalesced write-out
    for (int i = tid; i < 5 * BATCH_PER; i += NTH) {
        int o = i / BATCH_PER, p = i % BATCH_PER;
        out[(size_t)o * OUT_STRIDE + (size_t)b * BATCH_PER + p] = s_out[o][p];
    }
}

// ---------------------------------------------------------------------------
// Fallback: proven single kernel (one block per image, zero workspace).
// Used only if ws_size is too small for the key buffer + counters.
// ---------------------------------------------------------------------------
__global__ __launch_bounds__(NTH) void roiheads_fallback(
        const float* __restrict__ gt_boxes,
        const float* __restrict__ prop_boxes,
        const int*   __restrict__ gt_classes,
        const float* __restrict__ rand_pri,
        float*       __restrict__ out)
{
    __shared__ uint64_t s_keys[K_TOT];
    __shared__ uint64_t s_cand[2 * HALF_CAP];
    __shared__ int      s_hist[2][256];
    __shared__ float4   s_gtb4[M_GT];
    __shared__ int      s_gtc[M_GT];
    __shared__ float    s_out[5][BATCH_PER];
    __shared__ int      s_T[2], s_needed[2], s_cnt[2];

    const int b   = blockIdx.x;
    const int tid = threadIdx.x;

    for (int i = tid; i < 512; i += NTH) s_hist[i >> 8][i & 255] = 0;
    if (tid < 2) s_cnt[tid] = 0;
    for (int i = tid; i < M_GT; i += NTH)
        s_gtb4[i] = ((const float4*)gt_boxes)[(size_t)b * M_GT + i];
    for (int i = tid; i < M_GT; i += NTH)
        s_gtc[i] = gt_classes[(size_t)b * M_GT + i];
    __syncthreads();

    for (int k = tid; k < K_TOT; k += NTH) {
        float bx1, by1, bx2, by2;
        if (k < N_PROP) {
            const float4 bp = *(const float4*)(prop_boxes + ((size_t)b * N_PROP + k) * 4);
            bx1 = bp.x; by1 = bp.y; bx2 = bp.z; by2 = bp.w;
        } else {
            const float4 bp = s_gtb4[k - N_PROP];
            bx1 = bp.x; by1 = bp.y; bx2 = bp.z; by2 = bp.w;
        }
        float area_b;
        {
#pragma clang fp contract(off)
            area_b = (bx2 - bx1) * (by2 - by1);
        }
        float best = -1.0f; int bidx = 0;
        for (int m = 0; m < M_GT; ++m) {
            float iv = iou_g(s_gtb4[m], bx1, by1, bx2, by2, area_b);
            if (iv > best) { best = iv; bidx = m; }
        }
        const bool fg = best >= 0.5f;
        const float pri = rand_pri[(size_t)b * K_TOT + k];
        const uint32_t pb = __float_as_uint(pri);
        s_keys[k] = (fg ? (1ull << 50) : 0ull)
                  | ((uint64_t)pb << 20)
                  | ((uint64_t)k  << 7)
                  | (uint64_t)bidx;
        int bucket = min(255, (int)(pri * 256.0f));
        atomicAdd(&s_hist[fg ? 0 : 1][bucket], 1);
    }
    __syncthreads();

    for (int d = 1; d < 256; d <<= 1) {
        int v = 0, g = tid >> 8, t = tid & 255;
        bool act = (tid < 512) && (t + d < 256);
        if (act) v = s_hist[g][t + d];
        __syncthreads();
        if (act) s_hist[g][t] += v;
        __syncthreads();
    }

    if (tid == 0) {
        int fg_total = s_hist[0][0];
        int bg_total = s_hist[1][0];
        int nfg = min(NUM_FG_TGT, fg_total);
        int nbg = min(BATCH_PER - nfg, bg_total);
        s_needed[0] = nfg; s_needed[1] = nbg;
    }
    __syncthreads();

    if (tid < 512) {
        int g = tid >> 8, t = tid & 255;
        int need = s_needed[g];
        int St  = s_hist[g][t];
        int St1 = (t == 255) ? -1 : s_hist[g][t + 1];
        if (St >= need && St1 < need) s_T[g] = t;
    }
    if (tid < BATCH_PER) {
        s_out[0][tid] = 0.0f; s_out[1][tid] = -1.0f;
        s_out[2][tid] = -1.0f; s_out[3][tid] = -1.0f;
    }
    __syncthreads();

    const int nfg = s_needed[0], nbg = s_needed[1];
    if (tid < BATCH_PER)
        s_out[4][tid] = (tid < nfg + nbg) ? 1.0f : 0.0f;

    for (int k = tid; k < K_TOT; k += NTH) {
        uint64_t key = s_keys[k];
        int g = ((key >> 50) & 1ull) ? 0 : 1;
        uint32_t pbits = (uint32_t)((key >> 20) & 0x3FFFFFFFull);
        int bucket = min(255, (int)(__uint_as_float(pbits) * 256.0f));
        if (bucket >= s_T[g]) {
            int pos = atomicAdd(&s_cnt[g], 1);
            if (pos < HALF_CAP) s_cand[g * HALF_CAP + pos] = key;
        }
    }
    __syncthreads();

    const int fgc = min(s_cnt[0], HALF_CAP);
    const int bgc = min(s_cnt[1], HALF_CAP);
    for (int c = tid; c < fgc + bgc; c += NTH) {
        const bool isfg = (c < fgc);
        const int  base = isfg ? 0 : HALF_CAP;
        const int  cnt  = isfg ? fgc : bgc;
        const int  ci   = isfg ? c : (c - fgc);
        const uint64_t kc = s_cand[base + ci];
        int r = 0;
        for (int j = 0; j < cnt; ++j)
            r += (s_cand[base + j] > kc) ? 1 : 0;
        int slot = -1;
        if (isfg) { if (r < nfg) slot = r; }
        else      { if (r < nbg) slot = nfg + r; }
        if (slot >= 0) {
            int idx = (int)((kc >> 7) & 0x1FFFull);
            int mi  = (int)(kc & 0x7Full);
            float bx1, by1, bx2, by2;
            if (idx < N_PROP) {
                const float4 bp = *(const float4*)(prop_boxes + ((size_t)b * N_PROP + idx) * 4);
                bx1 = bp.x; by1 = bp.y; bx2 = bp.z; by2 = bp.w;
            } else {
                const float4 bp = s_gtb4[idx - N_PROP];
                bx1 = bp.x; by1 = bp.y; bx2 = bp.z; by2 = bp.w;
            }
            float area_b;
            {
#pragma clang fp contract(off)
                area_b = (bx2 - bx1) * (by2 - by1);
            }
            float iou = iou_g(s_gtb4[mi], bx1, by1, bx2, by2, area_b);
            s_out[0][slot] = iou;
            s_out[1][slot] = (float)idx;
            s_out[2][slot] = (float)(isfg ? s_gtc[mi] : NUM_CLASSES_);
            s_out[3][slot] = (float)mi;
        }
    }
    __syncthreads();

    for (int i = tid; i < 5 * BATCH_PER; i += NTH) {
        int o = i / BATCH_PER, p = i % BATCH_PER;
        out[(size_t)o * OUT_STRIDE + (size_t)b * BATCH_PER + p] = s_out[o][p];
    }
}

extern "C" void kernel_launch(void* const* d_in, const int* in_sizes, int n_in,
                              void* d_out, int out_size, void* d_ws, size_t ws_size,
                              hipStream_t stream) {
    const float* gt_boxes   = (const float*)d_in[0];  // [64,100,4]
    const float* prop_boxes = (const float*)d_in[1];  // [64,4000,4]
    const int*   gt_classes = (const int*)  d_in[2];  // [64,100]
    const float* rand_pri   = (const float*)d_in[3];  // [64,4100]
    float* out = (float*)d_out;                       // 5 x [64,512] float32, concat

    const size_t need_ws = CTR_BYTES + (size_t)B_IMG * K_TOT * sizeof(uint64_t);
    if (d_ws != nullptr && ws_size >= need_ws) {
        uint32_t* ctr  = (uint32_t*)d_ws;
        uint64_t* keys = (uint64_t*)((char*)d_ws + CTR_BYTES);
        // zero arrival counters (captured into the graph, ordered on stream)
        hipMemsetAsync(d_ws, 0, CTR_BYTES, stream);
        fused_kernel<<<B_IMG * QPI, NTH, 0, stream>>>(gt_boxes, prop_boxes,
                                                      gt_classes, rand_pri,
                                                      keys, ctr, out);
    } else {
        roiheads_fallback<<<B_IMG, NTH, 0, stream>>>(gt_boxes, prop_boxes,
                                                     gt_classes, rand_pri, out);
    }
}